// Round 13
// baseline (273.904 us; speedup 1.0000x reference)
//
#include <hip/hip_runtime.h>

#define B_ 256
#define T_ 128
#define D_ 768
#define K_ 74
#define C_ 128
#define TK_ 9472      // T_*K_
#define BT_ 32768     // B_*T_
#define EMS_ 18944    // B_*K_  (em time-slice stride)

#define LGKM_BARRIER() do { \
    asm volatile("s_waitcnt lgkmcnt(0)" ::: "memory"); \
    __builtin_amdgcn_s_barrier(); \
    __builtin_amdgcn_sched_barrier(0); \
} while (0)

// ---------------- K0: pad W1 -> W1q[4][768][20], W2 -> W2q[4][74][20]
__global__ void pad_weights(const float* __restrict__ W1, const float* __restrict__ W2,
                            float* __restrict__ W1q, float* __restrict__ W2q)
{
    int idx = blockIdx.x * 256 + threadIdx.x;
    if (idx < 4 * 768 * 20) {
        int nq = idx / (768 * 20); int rem = idx - nq * (768 * 20);
        int k = rem / 20, j = rem - k * 20;
        int c = nq * 19 + j;
        W1q[idx] = (j < 19 && c < 74) ? W1[k * 74 + c] : 0.f;
    }
    if (idx < 4 * 74 * 20) {
        int nq = idx / (74 * 20); int rem = idx - nq * (74 * 20);
        int k = rem / 20, j = rem - k * 20;
        int c = nq * 19 + j;
        W2q[idx] = (j < 19 && c < 74) ? W2[k * 74 + c] : 0.f;
    }
}

// ---------------- K1a: logits partials, K-split x3. ks -> {logits, y, em}
__global__ __launch_bounds__(256) void gemm_logits_part(const float* __restrict__ feats,
    const float* __restrict__ W1q, float* __restrict__ P0, float* __restrict__ P1,
    float* __restrict__ P2)
{
    int orig = blockIdx.x;                    // grid 1536 = 8 * 192
    int vb = (orig & 7) * 192 + (orig >> 3);
    int rb = vb / 12; int rem = vb - rb * 12;
    int nq = rem / 3, ks = rem - nq * 3;
    int tid = threadIdx.x;
    int r = rb * 256 + tid;
    int c0 = nq * 19;
    const float* frow = feats + (size_t)r * 768 + ks * 256;
    const float* wq = W1q + nq * (768 * 20) + ks * 256 * 20;
    float acc[20];
    #pragma unroll
    for (int j = 0; j < 20; ++j) acc[j] = 0.f;

    for (int k0 = 0; k0 < 256; k0 += 16) {
        float4 a[4];
        #pragma unroll
        for (int q = 0; q < 4; ++q) a[q] = *(const float4*)(frow + k0 + 4 * q);
        #pragma unroll
        for (int u = 0; u < 16; ++u) {
            float av = ((const float*)a)[u];
            const float* wr = wq + (k0 + u) * 20;
            #pragma unroll
            for (int j = 0; j < 20; ++j) acc[j] += av * wr[j];
        }
    }
    float* P = (ks == 0) ? P0 : ((ks == 1) ? P1 : P2);
    #pragma unroll
    for (int j = 0; j < 19; ++j) {
        int c = c0 + j;
        if (c < 74) P[(size_t)r * 74 + c] = acc[j];
    }
}

// ---------------- K1b: logits = P0 + P1 + P2 + b1
__global__ void logits_sum(const float* __restrict__ P1, const float* __restrict__ P2,
                           const float* __restrict__ b1, float* __restrict__ logits)
{
    int idx = blockIdx.x * 256 + threadIdx.x;
    int r = idx / 74; int c = idx - r * 74;
    logits[idx] = logits[idx] + P1[idx] + P2[idx] + b1[c];
}

// ---------------- K2: sim partials — 64 j-chunks (2 planes each), grid 512
__global__ __launch_bounds__(256) void sim_partial(const float* __restrict__ logits,
    const float* __restrict__ cache, float* __restrict__ part)
{
    __shared__ float As[74][68];
    __shared__ float Bs[74][68];
    int tid = threadIdx.x;
    int tx = tid & 15, ty = tid >> 4;
    int bid = blockIdx.x;                 // 512 = 64 jc x 4 mt x 2 nt
    int jc = bid >> 3;
    int mt = (bid >> 1) & 3;
    int nt = bid & 1;
    int p0 = mt * 64, q0 = nt * 64;
    float acc[4][4] = {};
    for (int jj = 0; jj < 2; ++jj) {
        int j = jc * 2 + jj;
        for (int it = 0; it < 19; ++it) {
            int lin = it * 256 + tid;
            if (lin < 64 * 74) {
                int r = lin / 74, ik = lin - r * 74;
                As[ik][r] = logits[(p0 + r) * TK_ + j * 74 + ik];
                Bs[ik][r] = cache[(q0 + r) * TK_ + j * 74 + ik];
            }
        }
        __syncthreads();
        for (int ik = 0; ik < 74; ++ik) {
            float4 a = *(const float4*)&As[ik][4 * tx];
            float4 b = *(const float4*)&Bs[ik][4 * ty];
            const float* ap = (const float*)&a;
            const float* bp = (const float*)&b;
            #pragma unroll
            for (int i = 0; i < 4; ++i)
                #pragma unroll
                for (int q = 0; q < 4; ++q) acc[i][q] += ap[i] * bp[q];
        }
        __syncthreads();
    }
    #pragma unroll
    for (int i = 0; i < 4; ++i)
        #pragma unroll
        for (int q = 0; q < 4; ++q)
            part[jc * (B_ * C_) + (p0 + 4 * tx + i) * C_ + q0 + 4 * ty + q] = acc[i][q];
}

__global__ void sim_reduce(const float* __restrict__ part, float* __restrict__ sim)
{
    int idx = blockIdx.x * 256 + threadIdx.x;
    float s = 0.f;
    for (int jc = 0; jc < 64; ++jc) s += part[jc * (B_ * C_) + idx];
    sim[idx] = s;
}

__global__ void softmax128(const float* __restrict__ sim, float* __restrict__ p)
{
    __shared__ float red[128];
    int q = threadIdx.x, row = blockIdx.x;
    float v = sim[row * 128 + q];
    red[q] = v; __syncthreads();
    for (int s = 64; s > 0; s >>= 1) { if (q < s) red[q] = fmaxf(red[q], red[q + s]); __syncthreads(); }
    float m = red[0]; __syncthreads();
    float e = expf(v - m);
    red[q] = e; __syncthreads();
    for (int s = 64; s > 0; s >>= 1) { if (q < s) red[q] += red[q + s]; __syncthreads(); }
    float sum = red[0];
    p[row * 128 + q] = e / sum;
}

// ---------------- K4a: y = logits + 0.5*(p @ c_r) — two K=64 stages
__global__ __launch_bounds__(256) void gemm_h_y(const float* __restrict__ pmat,
    const float* __restrict__ cache, const float* __restrict__ logits, float* __restrict__ y)
{
    __shared__ float As[64][68];
    __shared__ float Bs[64][68];
    int tid = threadIdx.x;
    int tx = tid & 15, ty = tid >> 4;
    int orig = blockIdx.x;                 // 592 = 8 x 74
    int vb = (orig & 7) * 74 + (orig >> 3);
    int mt = vb / 148, nt = vb - mt * 148;
    int r0 = mt * 64, n0 = nt * 64;
    float acc[4][4] = {};
    #pragma unroll
    for (int s = 0; s < 2; ++s) {
        #pragma unroll
        for (int it = 0; it < 16; ++it) {
            int lin = it * 256 + tid;
            int r = lin >> 6, kk = lin & 63;
            As[kk][r] = pmat[(r0 + r) * 128 + s * 64 + kk];
        }
        #pragma unroll
        for (int it = 0; it < 16; ++it) {
            int lin = it * 256 + tid;
            int kk = lin >> 6, c = lin & 63;
            Bs[kk][c] = cache[(s * 64 + kk) * TK_ + n0 + c];
        }
        __syncthreads();
        for (int kk = 0; kk < 64; ++kk) {
            float4 a = *(const float4*)&As[kk][4 * tx];
            float4 b = *(const float4*)&Bs[kk][4 * ty];
            const float* ap = (const float*)&a;
            const float* bp = (const float*)&b;
            #pragma unroll
            for (int i = 0; i < 4; ++i)
                #pragma unroll
                for (int j = 0; j < 4; ++j) acc[i][j] += ap[i] * bp[j];
        }
        __syncthreads();
    }
    #pragma unroll
    for (int i = 0; i < 4; ++i) {
        int r = r0 + 4 * tx + i;
        #pragma unroll
        for (int j = 0; j < 4; ++j) {
            int n = n0 + 4 * ty + j;
            y[r * TK_ + n] = logits[r * TK_ + n] + 0.5f * acc[i][j];
        }
    }
}

// ---------------- K4b: em = (y @ W2 + b2), transposed write
__global__ __launch_bounds__(256) void gemm_em(const float* __restrict__ y,
    const float* __restrict__ W2q, const float* __restrict__ b2, float* __restrict__ em)
{
    int orig = blockIdx.x;
    int vb = (orig & 7) * 64 + (orig >> 3);
    int rb = vb >> 2, nq = vb & 3;
    int tid = threadIdx.x;
    int r = rb * 256 + tid;
    int c0 = nq * 19;
    const float* wq = W2q + nq * (74 * 20);
    const float* yrow = y + (size_t)r * 74;
    float acc[20];
    #pragma unroll
    for (int j = 0; j < 20; ++j) acc[j] = 0.f;
    #pragma unroll 1
    for (int k0 = 0; k0 < 74; k0 += 2) {
        float2 a = *(const float2*)(yrow + k0);
        const float* ap = (const float*)&a;
        #pragma unroll
        for (int u = 0; u < 2; ++u) {
            const float* wr = wq + (k0 + u) * 20;
            #pragma unroll
            for (int j = 0; j < 20; ++j) acc[j] += ap[u] * wr[j];
        }
    }
    int b = r >> 7, t = r & 127;
    #pragma unroll
    for (int j = 0; j < 19; ++j) {
        int c = c0 + j;
        if (c < 74) em[t * EMS_ + b * 74 + c] = acc[j] + b2[c];
    }
}

// ---------------- K5: fused CRF scans — 5 waves, 4-lane groups per dest,
// in-register shfl reduction, ONE barrier per step.
__global__ __launch_bounds__(320) void crf_scan(const float* __restrict__ em,
    const int* __restrict__ mask_, const float* __restrict__ startv,
    const float* __restrict__ endv, const float* __restrict__ trans,
    float* __restrict__ out_tags, float* __restrict__ den)
{
    __shared__ float transS[74 * 74];
    __shared__ float scoreS[2][80] __attribute__((aligned(16)));
    __shared__ float EscS[2][80] __attribute__((aligned(16)));
    __shared__ unsigned char histS[127 * 74];
    __shared__ float tagsS[128];
    __shared__ float Ms[2];
    __shared__ int   flagU[5];
    __shared__ int   maskS[128];
    int tid = threadIdx.x;          // 0..319
    bool isV = blockIdx.x < 256;
    int b = isV ? blockIdx.x : (blockIdx.x - 256);

    for (int i = tid; i < 74 * 74; i += 320) transS[i] = trans[i];
    if (tid < 128) maskS[tid] = mask_[b * 128 + tid];
    if (tid >= 74 && tid < 80) {
        scoreS[0][tid] = -3.0e38f; scoreS[1][tid] = -3.0e38f;
        EscS[0][tid] = 0.f;        EscS[1][tid] = 0.f;
    }
    __syncthreads();

    int w = tid >> 6, lane = tid & 63;
    int destL = lane >> 2, subsrc = lane & 3;
    int dest = w * 16 + destL;            // 0..79
    bool isD = dest < 74;
    bool isOwner = (subsrc == 0) && isD;
    int kbase = subsrc * 20;              // 0,20,40,60

    float tr[20];
    #pragma unroll
    for (int j = 0; j < 20; ++j) {
        int k = kbase + j;
        tr[j] = (isD && k < 74) ? transS[k * 74 + dest] : -1.0e30f;
    }

    float prev = 0.f, eA = 0.f, eB = 0.f;
    if (isOwner) {
        prev = startv[dest] + em[b * 74 + dest];
        scoreS[0][dest] = prev;
        eA = em[1 * EMS_ + b * 74 + dest];
        eB = em[2 * EMS_ + b * 74 + dest];
    }
    __syncthreads();
    int cur = 0;

    if (isV) {
        for (int t = 1; t < 128; ++t) {
            float eC = 0.f;
            if (isOwner && t + 2 < 128) eC = em[(t + 2) * EMS_ + b * 74 + dest];
            float mA = -3.0e38f; int iA = kbase;
            float mB = -3.0e38f; int iB = kbase + 8;
            #pragma unroll
            for (int jj = 0; jj < 2; ++jj) {
                float4 s4 = *(const float4*)&scoreS[cur][kbase + 4 * jj];
                const float* sp = (const float*)&s4;
                #pragma unroll
                for (int u = 0; u < 4; ++u) {
                    float v = sp[u] + tr[4 * jj + u];
                    if (v > mA) { mA = v; iA = kbase + 4 * jj + u; }
                }
            }
            #pragma unroll
            for (int jj = 2; jj < 5; ++jj) {
                float4 s4 = *(const float4*)&scoreS[cur][kbase + 4 * jj];
                const float* sp = (const float*)&s4;
                #pragma unroll
                for (int u = 0; u < 4; ++u) {
                    float v = sp[u] + tr[4 * jj + u];
                    if (v > mB) { mB = v; iB = kbase + 4 * jj + u; }
                }
            }
            float m; int mi;
            if (mB > mA) { m = mB; mi = iB; } else { m = mA; mi = iA; }
            #pragma unroll
            for (int off = 1; off <= 2; off <<= 1) {
                float vo = __shfl_xor(m, off);
                int io = __shfl_xor(mi, off);
                if (vo > m || (vo == m && io < mi)) { m = vo; mi = io; }
            }
            int mk = maskS[t];
            if (isOwner) {
                histS[(t - 1) * 74 + dest] = (unsigned char)mi;
                float snew = mk ? (m + eA) : prev;
                scoreS[cur ^ 1][dest] = snew;
                prev = snew;
            }
            LGKM_BARRIER();
            cur ^= 1;
            eA = eB; eB = eC;
        }
        if (tid == 0) {
            float bm = scoreS[cur][0] + endv[0]; int bi = 0;
            for (int k = 1; k < 74; ++k) {
                float v = scoreS[cur][k] + endv[k];
                if (v > bm) { bm = v; bi = k; }
            }
            int curk = bi;
            tagsS[127] = (float)bi;
            for (int ti = 126; ti >= 0; --ti) {
                int mk = maskS[ti + 1];
                curk = mk ? (int)histS[ti * 74 + curk] : bi;
                tagsS[ti] = (float)curk;
            }
        }
        __syncthreads();
        if (tid < 128) out_tags[b * 128 + tid] = tagsS[tid];
    } else {
        #pragma unroll
        for (int j = 0; j < 20; ++j) tr[j] = __expf(tr[j]);   // pads -> 0
        float v0 = (tid < 74) ? scoreS[0][tid] : -3.0e38f;
        if (tid < 128) {
            #pragma unroll
            for (int off = 32; off > 0; off >>= 1) v0 = fmaxf(v0, __shfl_xor(v0, off));
            if ((tid & 63) == 0) Ms[tid >> 6] = v0;
        }
        __syncthreads();
        float M = fmaxf(Ms[0], Ms[1]);
        float Eprev = 0.f;
        if (isOwner) { Eprev = __expf(prev - M); EscS[0][dest] = Eprev; }
        int count = 0;
        LGKM_BARRIER();
        for (int t = 1; t < 128; ++t) {
            float eC = 0.f;
            if (isOwner && t + 2 < 128) eC = em[(t + 2) * EMS_ + b * 74 + dest];
            float s0 = 0.f, s1 = 0.f, s2 = 0.f, s3 = 0.f;
            #pragma unroll
            for (int jj = 0; jj < 5; ++jj) {
                float4 E4 = *(const float4*)&EscS[cur][kbase + 4 * jj];
                s0 += E4.x * tr[4 * jj + 0];
                s1 += E4.y * tr[4 * jj + 1];
                s2 += E4.z * tr[4 * jj + 2];
                s3 += E4.w * tr[4 * jj + 3];
            }
            float u = (s0 + s1) + (s2 + s3);
            u += __shfl_xor(u, 1);
            u += __shfl_xor(u, 2);
            int mk = maskS[t];
            int over = 0, notsmall = 0;
            if (isOwner) {
                float En = mk ? (u * __expf(eA)) : Eprev;
                EscS[cur ^ 1][dest] = En;
                Eprev = En;
                over = (En > 0x1p64f) ? 1 : 0;
                notsmall = (En >= 0x1p-32f) ? 1 : 0;
            }
            int wf = (__any(over) ? 1 : 0) | (__any(notsmall) ? 2 : 0);
            if (lane == 0) flagU[w] = wf;
            LGKM_BARRIER();
            cur ^= 1;
            int flO = 0, flN = 0;
            #pragma unroll
            for (int q = 0; q < 5; ++q) { flO |= flagU[q] & 1; flN |= flagU[q] & 2; }
            if (flO) {                           // overflow: exact /2^64
                if (isOwner) { Eprev *= 0x1p-64f; EscS[cur][dest] = Eprev; }
                count++;
                LGKM_BARRIER();
            } else if (!flN) {                   // underflow: exact *2^64
                if (isOwner) { Eprev *= 0x1p64f; EscS[cur][dest] = Eprev; }
                count--;
                LGKM_BARRIER();
            }
            eA = eB; eB = eC;
        }
        if (tid == 0) {
            float s = 0.f;
            for (int k = 0; k < 74; ++k) s += EscS[cur][k] * __expf(endv[k]);
            den[b] = M + (float)count * 44.36141955583650f + __logf(s);
        }
    }
}

// ---------------- K6: CRF score per batch, then final reduce
__global__ __launch_bounds__(128) void loss_partial(const float* __restrict__ em,
    const int* __restrict__ labels, const int* __restrict__ mask_,
    const float* __restrict__ startv, const float* __restrict__ endv,
    const float* __restrict__ den, const float* __restrict__ trans, float* __restrict__ nd)
{
    __shared__ float cs[2];
    __shared__ int ms[2];
    int b = blockIdx.x, t = threadIdx.x;
    int lab = labels[b * 128 + t];
    int mk = mask_[b * 128 + t];
    float contrib;
    if (t == 0) {
        contrib = startv[lab] + em[b * 74 + lab];
    } else {
        int labp = labels[b * 128 + t - 1];
        contrib = mk ? (trans[labp * 74 + lab] + em[t * EMS_ + b * 74 + lab]) : 0.f;
    }
    float c = contrib; int m = mk;
    #pragma unroll
    for (int off = 32; off > 0; off >>= 1) {
        c += __shfl_xor(c, off);
        m += __shfl_xor(m, off);
    }
    if ((t & 63) == 0) { cs[t >> 6] = c; ms[t >> 6] = m; }
    __syncthreads();
    if (t == 0) {
        float num = cs[0] + cs[1];
        int msum = ms[0] + ms[1];
        int last = labels[b * 128 + msum - 1];
        num += endv[last];
        nd[b] = num - den[b];
    }
}

__global__ void loss_final(const float* __restrict__ nd, float* __restrict__ out_loss)
{
    __shared__ float red[256];
    int i = threadIdx.x;
    red[i] = nd[i];
    __syncthreads();
    for (int s = 128; s > 0; s >>= 1) { if (i < s) red[i] += red[i + s]; __syncthreads(); }
    if (i == 0) out_loss[0] = -(red[0] / 256.f);
}

extern "C" void kernel_launch(void* const* d_in, const int* in_sizes, int n_in,
                              void* d_out, int out_size, void* d_ws, size_t ws_size,
                              hipStream_t stream)
{
    const float* feats  = (const float*)d_in[0];
    const int*   amask  = (const int*)d_in[1];
    const int*   labels = (const int*)d_in[2];
    const float* cache  = (const float*)d_in[3];
    const float* W1     = (const float*)d_in[4];
    const float* b1     = (const float*)d_in[5];
    const float* W2     = (const float*)d_in[6];
    const float* b2     = (const float*)d_in[7];
    const float* startv = (const float*)d_in[8];
    const float* endv   = (const float*)d_in[9];
    const float* trans  = (const float*)d_in[10];

    float* ws     = (float*)d_ws;
    float* logits = ws;                 // 2,424,832
    float* y      = ws + 2424832;       // 2,424,832 (K-split P1, then sim part[64], then y)
    float* em     = ws + 4849664;       // 2,424,832 (K-split P2, then em)
    float* scratch= ws + 7274496;       // 1,048,576 (W1q alias)
    float* sim    = ws + 8323072;       // 32,768
    float* p      = ws + 8355840;       // 32,768
    float* den    = ws + 8388608;       // 256
    float* nd     = ws + 8388864;       // 256
    float* W2q    = ws + 8389120;       // 5,920
    float* W1q    = scratch;            // 61,440 — dead before sim_partial runs
    float* part   = y;                  // 64*32768 = 2,097,152 ≤ 2,424,832
    float* out_tags = (float*)d_out;
    float* out_loss = (float*)d_out + 32768;

    hipLaunchKernelGGL(pad_weights,      dim3(240),  dim3(256), 0, stream, W1, W2, W1q, W2q);
    hipLaunchKernelGGL(gemm_logits_part, dim3(1536), dim3(256), 0, stream, feats, W1q, logits, y, em);
    hipLaunchKernelGGL(logits_sum,       dim3(9472), dim3(256), 0, stream, y, em, b1, logits);
    hipLaunchKernelGGL(sim_partial,      dim3(512),  dim3(256), 0, stream, logits, cache, part);
    hipLaunchKernelGGL(sim_reduce,       dim3(128),  dim3(256), 0, stream, part, sim);
    hipLaunchKernelGGL(softmax128,       dim3(256),  dim3(128), 0, stream, sim, p);
    hipLaunchKernelGGL(gemm_h_y,         dim3(592),  dim3(256), 0, stream, p, cache, logits, y);
    hipLaunchKernelGGL(gemm_em,          dim3(512),  dim3(256), 0, stream, y, W2q, b2, em);
    hipLaunchKernelGGL(crf_scan,         dim3(512),  dim3(320), 0, stream, em, amask, startv, endv, trans, out_tags, den);
    hipLaunchKernelGGL(loss_partial,     dim3(256),  dim3(128), 0, stream, em, labels, amask, startv, endv, den, trans, nd);
    hipLaunchKernelGGL(loss_final,       dim3(1),    dim3(256), 0, stream, nd, out_loss);
}

// Round 14
// 250.253 us; speedup vs baseline: 1.0945x; 1.0945x over previous
//
#include <hip/hip_runtime.h>

#define B_ 256
#define T_ 128
#define D_ 768
#define K_ 74
#define C_ 128
#define TK_ 9472      // T_*K_
#define BT_ 32768     // B_*T_
#define EMS_ 18944    // B_*K_  (em time-slice stride)

#define LGKM_BARRIER() do { \
    asm volatile("s_waitcnt lgkmcnt(0)" ::: "memory"); \
    __builtin_amdgcn_s_barrier(); \
    __builtin_amdgcn_sched_barrier(0); \
} while (0)

// ---------------- K0: pad W1 -> W1q[4][768][20], W2 -> W2q[4][74][20]
__global__ void pad_weights(const float* __restrict__ W1, const float* __restrict__ W2,
                            float* __restrict__ W1q, float* __restrict__ W2q)
{
    int idx = blockIdx.x * 256 + threadIdx.x;
    if (idx < 4 * 768 * 20) {
        int nq = idx / (768 * 20); int rem = idx - nq * (768 * 20);
        int k = rem / 20, j = rem - k * 20;
        int c = nq * 19 + j;
        W1q[idx] = (j < 19 && c < 74) ? W1[k * 74 + c] : 0.f;
    }
    if (idx < 4 * 74 * 20) {
        int nq = idx / (74 * 20); int rem = idx - nq * (74 * 20);
        int k = rem / 20, j = rem - k * 20;
        int c = nq * 19 + j;
        W2q[idx] = (j < 19 && c < 74) ? W2[k * 74 + c] : 0.f;
    }
}

// ---------------- K1a: logits partials, K-split x2 (R12 config: grid 1024, K=384)
__global__ __launch_bounds__(256) void gemm_logits_part(const float* __restrict__ feats,
    const float* __restrict__ W1q, float* __restrict__ outA, float* __restrict__ outB)
{
    int orig = blockIdx.x;                    // grid 1024
    int vb = (orig & 7) * 128 + (orig >> 3);
    int rb = vb >> 3, nq = (vb >> 1) & 3, ks = vb & 1;
    int tid = threadIdx.x;
    int r = rb * 256 + tid;
    int c0 = nq * 19;
    const float* frow = feats + (size_t)r * 768 + ks * 384;
    const float* wq = W1q + nq * (768 * 20) + ks * 384 * 20;
    float acc[20];
    #pragma unroll
    for (int j = 0; j < 20; ++j) acc[j] = 0.f;

    for (int k0 = 0; k0 < 384; k0 += 16) {
        float4 a[4];
        #pragma unroll
        for (int q = 0; q < 4; ++q) a[q] = *(const float4*)(frow + k0 + 4 * q);
        #pragma unroll
        for (int u = 0; u < 16; ++u) {
            float av = ((const float*)a)[u];
            const float* wr = wq + (k0 + u) * 20;
            #pragma unroll
            for (int j = 0; j < 20; ++j) acc[j] += av * wr[j];
        }
    }
    float* P = ks ? outB : outA;
    #pragma unroll
    for (int j = 0; j < 19; ++j) {
        int c = c0 + j;
        if (c < 74) P[(size_t)r * 74 + c] = acc[j];
    }
}

// ---------------- K1b: logits = A + B + b1
__global__ void logits_sum(const float* __restrict__ Bp, const float* __restrict__ b1,
                           float* __restrict__ logits)
{
    int idx = blockIdx.x * 256 + threadIdx.x;
    int r = idx / 74; int c = idx - r * 74;
    logits[idx] = logits[idx] + Bp[idx] + b1[c];
}

// ---------------- K2: sim partials — 64 j-chunks (2 planes each), grid 512
__global__ __launch_bounds__(256) void sim_partial(const float* __restrict__ logits,
    const float* __restrict__ cache, float* __restrict__ part)
{
    __shared__ float As[74][68];
    __shared__ float Bs[74][68];
    int tid = threadIdx.x;
    int tx = tid & 15, ty = tid >> 4;
    int bid = blockIdx.x;                 // 512 = 64 jc x 4 mt x 2 nt
    int jc = bid >> 3;
    int mt = (bid >> 1) & 3;
    int nt = bid & 1;
    int p0 = mt * 64, q0 = nt * 64;
    float acc[4][4] = {};
    for (int jj = 0; jj < 2; ++jj) {
        int j = jc * 2 + jj;
        for (int it = 0; it < 19; ++it) {
            int lin = it * 256 + tid;
            if (lin < 64 * 74) {
                int r = lin / 74, ik = lin - r * 74;
                As[ik][r] = logits[(p0 + r) * TK_ + j * 74 + ik];
                Bs[ik][r] = cache[(q0 + r) * TK_ + j * 74 + ik];
            }
        }
        __syncthreads();
        for (int ik = 0; ik < 74; ++ik) {
            float4 a = *(const float4*)&As[ik][4 * tx];
            float4 b = *(const float4*)&Bs[ik][4 * ty];
            const float* ap = (const float*)&a;
            const float* bp = (const float*)&b;
            #pragma unroll
            for (int i = 0; i < 4; ++i)
                #pragma unroll
                for (int q = 0; q < 4; ++q) acc[i][q] += ap[i] * bp[q];
        }
        __syncthreads();
    }
    #pragma unroll
    for (int i = 0; i < 4; ++i)
        #pragma unroll
        for (int q = 0; q < 4; ++q)
            part[jc * (B_ * C_) + (p0 + 4 * tx + i) * C_ + q0 + 4 * ty + q] = acc[i][q];
}

__global__ void sim_reduce(const float* __restrict__ part, float* __restrict__ sim)
{
    int idx = blockIdx.x * 256 + threadIdx.x;
    float s = 0.f;
    for (int jc = 0; jc < 64; ++jc) s += part[jc * (B_ * C_) + idx];
    sim[idx] = s;
}

__global__ void softmax128(const float* __restrict__ sim, float* __restrict__ p)
{
    __shared__ float red[128];
    int q = threadIdx.x, row = blockIdx.x;
    float v = sim[row * 128 + q];
    red[q] = v; __syncthreads();
    for (int s = 64; s > 0; s >>= 1) { if (q < s) red[q] = fmaxf(red[q], red[q + s]); __syncthreads(); }
    float m = red[0]; __syncthreads();
    float e = expf(v - m);
    red[q] = e; __syncthreads();
    for (int s = 64; s > 0; s >>= 1) { if (q < s) red[q] += red[q + s]; __syncthreads(); }
    float sum = red[0];
    p[row * 128 + q] = e / sum;
}

// ---------------- K4a: y = logits + 0.5*(p @ c_r) — two K=64 stages
__global__ __launch_bounds__(256) void gemm_h_y(const float* __restrict__ pmat,
    const float* __restrict__ cache, const float* __restrict__ logits, float* __restrict__ y)
{
    __shared__ float As[64][68];
    __shared__ float Bs[64][68];
    int tid = threadIdx.x;
    int tx = tid & 15, ty = tid >> 4;
    int orig = blockIdx.x;                 // 592 = 8 x 74
    int vb = (orig & 7) * 74 + (orig >> 3);
    int mt = vb / 148, nt = vb - mt * 148;
    int r0 = mt * 64, n0 = nt * 64;
    float acc[4][4] = {};
    #pragma unroll
    for (int s = 0; s < 2; ++s) {
        #pragma unroll
        for (int it = 0; it < 16; ++it) {
            int lin = it * 256 + tid;
            int r = lin >> 6, kk = lin & 63;
            As[kk][r] = pmat[(r0 + r) * 128 + s * 64 + kk];
        }
        #pragma unroll
        for (int it = 0; it < 16; ++it) {
            int lin = it * 256 + tid;
            int kk = lin >> 6, c = lin & 63;
            Bs[kk][c] = cache[(s * 64 + kk) * TK_ + n0 + c];
        }
        __syncthreads();
        for (int kk = 0; kk < 64; ++kk) {
            float4 a = *(const float4*)&As[kk][4 * tx];
            float4 b = *(const float4*)&Bs[kk][4 * ty];
            const float* ap = (const float*)&a;
            const float* bp = (const float*)&b;
            #pragma unroll
            for (int i = 0; i < 4; ++i)
                #pragma unroll
                for (int j = 0; j < 4; ++j) acc[i][j] += ap[i] * bp[j];
        }
        __syncthreads();
    }
    #pragma unroll
    for (int i = 0; i < 4; ++i) {
        int r = r0 + 4 * tx + i;
        #pragma unroll
        for (int j = 0; j < 4; ++j) {
            int n = n0 + 4 * ty + j;
            y[r * TK_ + n] = logits[r * TK_ + n] + 0.5f * acc[i][j];
        }
    }
}

// ---------------- K4b: em = (y @ W2 + b2), transposed write
__global__ __launch_bounds__(256) void gemm_em(const float* __restrict__ y,
    const float* __restrict__ W2q, const float* __restrict__ b2, float* __restrict__ em)
{
    int orig = blockIdx.x;
    int vb = (orig & 7) * 64 + (orig >> 3);
    int rb = vb >> 2, nq = vb & 3;
    int tid = threadIdx.x;
    int r = rb * 256 + tid;
    int c0 = nq * 19;
    const float* wq = W2q + nq * (74 * 20);
    const float* yrow = y + (size_t)r * 74;
    float acc[20];
    #pragma unroll
    for (int j = 0; j < 20; ++j) acc[j] = 0.f;
    #pragma unroll 1
    for (int k0 = 0; k0 < 74; k0 += 2) {
        float2 a = *(const float2*)(yrow + k0);
        const float* ap = (const float*)&a;
        #pragma unroll
        for (int u = 0; u < 2; ++u) {
            const float* wr = wq + (k0 + u) * 20;
            #pragma unroll
            for (int j = 0; j < 20; ++j) acc[j] += ap[u] * wr[j];
        }
    }
    int b = r >> 7, t = r & 127;
    #pragma unroll
    for (int j = 0; j < 19; ++j) {
        int c = c0 + j;
        if (c < 74) em[t * EMS_ + b * 74 + c] = acc[j] + b2[c];
    }
}

// ---------------- K5: fused CRF scans — 5 waves, 4-lane groups per dest,
// one barrier per step, mask in register bitmask (ballot).
__global__ __launch_bounds__(320) void crf_scan(const float* __restrict__ em,
    const int* __restrict__ mask_, const float* __restrict__ startv,
    const float* __restrict__ endv, const float* __restrict__ trans,
    float* __restrict__ out_tags, float* __restrict__ den)
{
    __shared__ float transS[74 * 74];
    __shared__ float scoreS[2][80] __attribute__((aligned(16)));
    __shared__ float EscS[2][80] __attribute__((aligned(16)));
    __shared__ unsigned char histS[127 * 74];
    __shared__ float tagsS[128];
    __shared__ float Ms[2];
    __shared__ int   flagU[5];
    __shared__ int   maskS[128];
    int tid = threadIdx.x;          // 0..319
    bool isV = blockIdx.x < 256;
    int b = isV ? blockIdx.x : (blockIdx.x - 256);

    for (int i = tid; i < 74 * 74; i += 320) transS[i] = trans[i];
    if (tid < 128) maskS[tid] = mask_[b * 128 + tid];
    if (tid >= 74 && tid < 80) {
        scoreS[0][tid] = -3.0e38f; scoreS[1][tid] = -3.0e38f;
        EscS[0][tid] = 0.f;        EscS[1][tid] = 0.f;
    }
    __syncthreads();

    int w = tid >> 6, lane = tid & 63;
    // mask as register bitmask: bit t of mb0/mb1 = mask[t]/mask[64+t]
    unsigned long long mb0 = __ballot(maskS[lane] != 0);
    unsigned long long mb1 = __ballot(maskS[64 + lane] != 0);

    int destL = lane >> 2, subsrc = lane & 3;
    int dest = w * 16 + destL;            // 0..79
    bool isD = dest < 74;
    bool isOwner = (subsrc == 0) && isD;
    int kbase = subsrc * 20;              // 0,20,40,60

    float tr[20];
    #pragma unroll
    for (int j = 0; j < 20; ++j) {
        int k = kbase + j;
        tr[j] = (isD && k < 74) ? transS[k * 74 + dest] : -1.0e30f;
    }

    float prev = 0.f, eA = 0.f, eB = 0.f;
    if (isOwner) {
        prev = startv[dest] + em[b * 74 + dest];
        scoreS[0][dest] = prev;
        eA = em[1 * EMS_ + b * 74 + dest];
        eB = em[2 * EMS_ + b * 74 + dest];
    }
    __syncthreads();
    int cur = 0;

    if (isV) {
        for (int t = 1; t < 128; ++t) {
            float eC = 0.f;
            if (isOwner && t + 2 < 128) eC = em[(t + 2) * EMS_ + b * 74 + dest];
            float mA = -3.0e38f; int iA = kbase;
            float mB = -3.0e38f; int iB = kbase + 8;
            #pragma unroll
            for (int jj = 0; jj < 2; ++jj) {
                float4 s4 = *(const float4*)&scoreS[cur][kbase + 4 * jj];
                const float* sp = (const float*)&s4;
                #pragma unroll
                for (int u = 0; u < 4; ++u) {
                    float v = sp[u] + tr[4 * jj + u];
                    if (v > mA) { mA = v; iA = kbase + 4 * jj + u; }
                }
            }
            #pragma unroll
            for (int jj = 2; jj < 5; ++jj) {
                float4 s4 = *(const float4*)&scoreS[cur][kbase + 4 * jj];
                const float* sp = (const float*)&s4;
                #pragma unroll
                for (int u = 0; u < 4; ++u) {
                    float v = sp[u] + tr[4 * jj + u];
                    if (v > mB) { mB = v; iB = kbase + 4 * jj + u; }
                }
            }
            float m; int mi;
            if (mB > mA) { m = mB; mi = iB; } else { m = mA; mi = iA; }
            #pragma unroll
            for (int off = 1; off <= 2; off <<= 1) {
                float vo = __shfl_xor(m, off);
                int io = __shfl_xor(mi, off);
                if (vo > m || (vo == m && io < mi)) { m = vo; mi = io; }
            }
            int mk = (int)(((t < 64) ? (mb0 >> t) : (mb1 >> (t - 64))) & 1ULL);
            if (isOwner) {
                histS[(t - 1) * 74 + dest] = (unsigned char)mi;
                float snew = mk ? (m + eA) : prev;
                scoreS[cur ^ 1][dest] = snew;
                prev = snew;
            }
            LGKM_BARRIER();
            cur ^= 1;
            eA = eB; eB = eC;
        }
        if (tid == 0) {
            float bm = scoreS[cur][0] + endv[0]; int bi = 0;
            for (int k = 1; k < 74; ++k) {
                float v = scoreS[cur][k] + endv[k];
                if (v > bm) { bm = v; bi = k; }
            }
            int curk = bi;
            tagsS[127] = (float)bi;
            for (int ti = 126; ti >= 0; --ti) {
                int mk = maskS[ti + 1];
                curk = mk ? (int)histS[ti * 74 + curk] : bi;
                tagsS[ti] = (float)curk;
            }
        }
        __syncthreads();
        if (tid < 128) out_tags[b * 128 + tid] = tagsS[tid];
    } else {
        #pragma unroll
        for (int j = 0; j < 20; ++j) tr[j] = __expf(tr[j]);   // pads -> 0
        float v0 = (tid < 74) ? scoreS[0][tid] : -3.0e38f;
        if (tid < 128) {
            #pragma unroll
            for (int off = 32; off > 0; off >>= 1) v0 = fmaxf(v0, __shfl_xor(v0, off));
            if ((tid & 63) == 0) Ms[tid >> 6] = v0;
        }
        __syncthreads();
        float M = fmaxf(Ms[0], Ms[1]);
        float Eprev = 0.f;
        if (isOwner) { Eprev = __expf(prev - M); EscS[0][dest] = Eprev; }
        int count = 0;
        LGKM_BARRIER();
        for (int t = 1; t < 128; ++t) {
            float eC = 0.f;
            if (isOwner && t + 2 < 128) eC = em[(t + 2) * EMS_ + b * 74 + dest];
            float s0 = 0.f, s1 = 0.f, s2 = 0.f, s3 = 0.f;
            #pragma unroll
            for (int jj = 0; jj < 5; ++jj) {
                float4 E4 = *(const float4*)&EscS[cur][kbase + 4 * jj];
                s0 += E4.x * tr[4 * jj + 0];
                s1 += E4.y * tr[4 * jj + 1];
                s2 += E4.z * tr[4 * jj + 2];
                s3 += E4.w * tr[4 * jj + 3];
            }
            float u = (s0 + s1) + (s2 + s3);
            u += __shfl_xor(u, 1);
            u += __shfl_xor(u, 2);
            int mk = (int)(((t < 64) ? (mb0 >> t) : (mb1 >> (t - 64))) & 1ULL);
            int over = 0, notsmall = 0;
            if (isOwner) {
                float En = mk ? (u * __expf(eA)) : Eprev;
                EscS[cur ^ 1][dest] = En;
                Eprev = En;
                over = (En > 0x1p64f) ? 1 : 0;
                notsmall = (En >= 0x1p-32f) ? 1 : 0;
            }
            int wf = (__any(over) ? 1 : 0) | (__any(notsmall) ? 2 : 0);
            if (lane == 0) flagU[w] = wf;
            LGKM_BARRIER();
            cur ^= 1;
            int flO = 0, flN = 0;
            #pragma unroll
            for (int q = 0; q < 5; ++q) { flO |= flagU[q] & 1; flN |= flagU[q] & 2; }
            if (flO) {                           // overflow: exact /2^64
                if (isOwner) { Eprev *= 0x1p-64f; EscS[cur][dest] = Eprev; }
                count++;
                LGKM_BARRIER();
            } else if (!flN) {                   // underflow: exact *2^64
                if (isOwner) { Eprev *= 0x1p64f; EscS[cur][dest] = Eprev; }
                count--;
                LGKM_BARRIER();
            }
            eA = eB; eB = eC;
        }
        if (tid == 0) {
            float s = 0.f;
            for (int k = 0; k < 74; ++k) s += EscS[cur][k] * __expf(endv[k]);
            den[b] = M + (float)count * 44.36141955583650f + __logf(s);
        }
    }
}

// ---------------- K6: CRF score per batch, then final reduce
__global__ __launch_bounds__(128) void loss_partial(const float* __restrict__ em,
    const int* __restrict__ labels, const int* __restrict__ mask_,
    const float* __restrict__ startv, const float* __restrict__ endv,
    const float* __restrict__ den, const float* __restrict__ trans, float* __restrict__ nd)
{
    __shared__ float cs[2];
    __shared__ int ms[2];
    int b = blockIdx.x, t = threadIdx.x;
    int lab = labels[b * 128 + t];
    int mk = mask_[b * 128 + t];
    float contrib;
    if (t == 0) {
        contrib = startv[lab] + em[b * 74 + lab];
    } else {
        int labp = labels[b * 128 + t - 1];
        contrib = mk ? (trans[labp * 74 + lab] + em[t * EMS_ + b * 74 + lab]) : 0.f;
    }
    float c = contrib; int m = mk;
    #pragma unroll
    for (int off = 32; off > 0; off >>= 1) {
        c += __shfl_xor(c, off);
        m += __shfl_xor(m, off);
    }
    if ((t & 63) == 0) { cs[t >> 6] = c; ms[t >> 6] = m; }
    __syncthreads();
    if (t == 0) {
        float num = cs[0] + cs[1];
        int msum = ms[0] + ms[1];
        int last = labels[b * 128 + msum - 1];
        num += endv[last];
        nd[b] = num - den[b];
    }
}

__global__ void loss_final(const float* __restrict__ nd, float* __restrict__ out_loss)
{
    __shared__ float red[256];
    int i = threadIdx.x;
    red[i] = nd[i];
    __syncthreads();
    for (int s = 128; s > 0; s >>= 1) { if (i < s) red[i] += red[i + s]; __syncthreads(); }
    if (i == 0) out_loss[0] = -(red[0] / 256.f);
}

extern "C" void kernel_launch(void* const* d_in, const int* in_sizes, int n_in,
                              void* d_out, int out_size, void* d_ws, size_t ws_size,
                              hipStream_t stream)
{
    const float* feats  = (const float*)d_in[0];
    const int*   amask  = (const int*)d_in[1];
    const int*   labels = (const int*)d_in[2];
    const float* cache  = (const float*)d_in[3];
    const float* W1     = (const float*)d_in[4];
    const float* b1     = (const float*)d_in[5];
    const float* W2     = (const float*)d_in[6];
    const float* b2     = (const float*)d_in[7];
    const float* startv = (const float*)d_in[8];
    const float* endv   = (const float*)d_in[9];
    const float* trans  = (const float*)d_in[10];

    float* ws     = (float*)d_ws;
    float* logits = ws;                 // 2,424,832
    float* y      = ws + 2424832;       // 2,424,832 (K-split P1, then sim part[64], then y)
    float* em     = ws + 4849664;       // 2,424,832
    float* scratch= ws + 7274496;       // 1,048,576 (W1q alias)
    float* sim    = ws + 8323072;       // 32,768
    float* p      = ws + 8355840;       // 32,768
    float* den    = ws + 8388608;       // 256
    float* nd     = ws + 8388864;       // 256
    float* W2q    = ws + 8389120;       // 5,920
    float* W1q    = scratch;            // 61,440 — dead before sim_partial runs
    float* part   = y;                  // 64*32768 = 2,097,152 ≤ 2,424,832
    float* out_tags = (float*)d_out;
    float* out_loss = (float*)d_out + 32768;

    hipLaunchKernelGGL(pad_weights,      dim3(240),  dim3(256), 0, stream, W1, W2, W1q, W2q);
    hipLaunchKernelGGL(gemm_logits_part, dim3(1024), dim3(256), 0, stream, feats, W1q, logits, y);
    hipLaunchKernelGGL(logits_sum,       dim3(9472), dim3(256), 0, stream, y, b1, logits);
    hipLaunchKernelGGL(sim_partial,      dim3(512),  dim3(256), 0, stream, logits, cache, part);
    hipLaunchKernelGGL(sim_reduce,       dim3(128),  dim3(256), 0, stream, part, sim);
    hipLaunchKernelGGL(softmax128,       dim3(256),  dim3(128), 0, stream, sim, p);
    hipLaunchKernelGGL(gemm_h_y,         dim3(592),  dim3(256), 0, stream, p, cache, logits, y);
    hipLaunchKernelGGL(gemm_em,          dim3(512),  dim3(256), 0, stream, y, W2q, b2, em);
    hipLaunchKernelGGL(crf_scan,         dim3(512),  dim3(320), 0, stream, em, amask, startv, endv, trans, out_tags, den);
    hipLaunchKernelGGL(loss_partial,     dim3(256),  dim3(128), 0, stream, em, labels, amask, startv, endv, den, trans, nd);
    hipLaunchKernelGGL(loss_final,       dim3(1),    dim3(256), 0, stream, nd, out_loss);
}